// Round 2
// baseline (184.412 us; speedup 1.0000x reference)
//
#include <hip/hip_runtime.h>
#include <hip/hip_bf16.h>
#include <hip/hip_cooperative_groups.h>

namespace cg = cooperative_groups;

#define TT 2048
#define DD 256
#define HH 256

#define GL_DECAY 0.891f        /* DISCOUNT * LAMBDA = 0.99*0.9 */
#define ALPHA    0.01f

#define NBLK 512               /* 2 blocks/CU on 256 CUs */
#define NTHR 256

// ---------------- workspace layout (floats) ----------------
#define OFF_H   0               /* Hbuf: T x H  = 524288 */
#define OFF_G   524288          /* Gbuf: T x H  = 524288 */
#define OFF_U   1048576         /* u:    T      = 2048   */
#define OFF_PW1 1050624         /* partW1: 16 x 65536 = 1048576 */
#define OFF_PB1 2099200         /* partB1: 16 x 256 = 4096 */
#define OFF_PW2 2103296         /* partW2: 16 x 256 = 4096 */
#define WS_FLOATS 2107392       /* ~8.04 MB */

__global__ __launch_bounds__(NTHR, 2) void fused_kernel(
    const float* __restrict__ xs, const float* __restrict__ ys,
    const float* __restrict__ W1, const float* __restrict__ b1,
    const float* __restrict__ W2, const float* __restrict__ b2,
    float* __restrict__ Hbuf, float* __restrict__ Gbuf, float* __restrict__ u,
    float* __restrict__ pW1, float* __restrict__ pB1, float* __restrict__ pW2,
    float* __restrict__ outp) {
  cg::grid_group grid = cg::this_grid();
  const int j = threadIdx.x;
  const int blk = blockIdx.x;

  __shared__ float c_lds[TT];      // 8 KB, persists B -> C
  __shared__ float scr[1024];      // 4 KB scratch, reused per stage

  // ================= Stage A: forward =================
  // block -> rows [4*blk, 4*blk+4); thread j -> column j.
  // A = xs@W1 + b1; H = relu(A); G = (A>0)?W2:0; u = H@W2 + b2
  {
    const int r0 = blk * 4;
    const float bj = b1[j];
    float acc[4] = {bj, bj, bj, bj};
#pragma unroll 8
    for (int k = 0; k < DD; ++k) {
      float w = W1[k * HH + j];                 // coalesced vector load
#pragma unroll
      for (int r = 0; r < 4; ++r)
        acc[r] = fmaf(xs[(r0 + r) * DD + k], w, acc[r]);  // uniform -> s_load
    }
    const float w2j = W2[j];
    float (*red)[256] = (float (*)[256])scr;
#pragma unroll
    for (int r = 0; r < 4; ++r) {
      float a = acc[r];
      float h = fmaxf(a, 0.0f);
      float g = (a > 0.0f) ? w2j : 0.0f;
      Hbuf[(r0 + r) * HH + j] = h;
      Gbuf[(r0 + r) * HH + j] = g;
      red[r][j] = h * w2j;
    }
    __syncthreads();
    for (int s = 128; s >= 1; s >>= 1) {
      if (j < s) {
#pragma unroll
        for (int r = 0; r < 4; ++r) red[r][j] += red[r][j + s];
      }
      __syncthreads();
    }
    if (j < 4) u[r0 + j] = red[j][0] + b2[0];
  }

  grid.sync();

  // ================= Stage B: scans (replicated per block) =================
  // Forward:  sigma_t = e_t - r_{t-1};  r_t = keep_t*((1-a)r_{t-1} + a*e_t)
  // Backward: c_t = gl*keep_t*c_{t+1} - sigma_t          (c kept in LDS)
  {
    const int t = j;
    const int base = t * 8;
    float e[8], keep[8];
#pragma unroll
    for (int i = 0; i < 8; ++i) {
      float g = ys[(base + i) * 2 + 0];
      float done = ys[(base + i) * 2 + 1];
      float d = g - u[base + i];
      e[i] = d * d;
      keep[i] = (done > 0.5f) ? 0.0f : 1.0f;
    }
    float A = 1.0f, B = 0.0f;
#pragma unroll
    for (int i = 0; i < 8; ++i) {
      float a = keep[i] * (1.0f - ALPHA);
      float b = keep[i] * (ALPHA * e[i]);
      A = a * A;
      B = a * B + b;
    }
    float* As = scr;
    float* Bs = scr + 256;
    As[t] = A; Bs[t] = B;
    __syncthreads();
    for (int s = 1; s < 256; s <<= 1) {      // inclusive scan L->R
      float pA = 1.0f, pB = 0.0f;
      if (t >= s) { pA = As[t - s]; pB = Bs[t - s]; }
      __syncthreads();
      float nA = A * pA;
      float nB = A * pB + B;
      A = nA; B = nB;
      As[t] = A; Bs[t] = B;
      __syncthreads();
    }
    float r = (t == 0) ? 0.0f : Bs[t - 1];
    float sig[8];
#pragma unroll
    for (int i = 0; i < 8; ++i) {
      sig[i] = e[i] - r;
      float a = keep[i] * (1.0f - ALPHA);
      float b = keep[i] * (ALPHA * e[i]);
      r = a * r + b;
    }
    if (blk == 0 && t == 255) outp[66049] = sig[7];   // sigmas[-1]

    float A2 = 1.0f, B2 = 0.0f;
#pragma unroll
    for (int i = 7; i >= 0; --i) {
      float a = GL_DECAY * keep[i];
      float nA = a * A2;
      float nB = a * B2 - sig[i];
      A2 = nA; B2 = nB;
    }
    __syncthreads();
    As[t] = A2; Bs[t] = B2;
    __syncthreads();
    for (int s = 1; s < 256; s <<= 1) {      // inclusive scan R->L
      float pA = 1.0f, pB = 0.0f;
      if (t + s < 256) { pA = As[t + s]; pB = Bs[t + s]; }
      __syncthreads();
      float nA = A2 * pA;
      float nB = A2 * pB + B2;
      A2 = nA; B2 = nB;
      As[t] = A2; Bs[t] = B2;
      __syncthreads();
    }
    float cin = (t == 255) ? 0.0f : Bs[t + 1];
    float csum = 0.0f;
#pragma unroll
    for (int i = 7; i >= 0; --i) {
      float a = GL_DECAY * keep[i];
      cin = a * cin - sig[i];
      c_lds[base + i] = cin;
      csum += cin;
    }
    if (blk == 0) {                          // total_b2 = sum(c)
      __syncthreads();
      As[t] = csum;
      __syncthreads();
      for (int s = 128; s >= 1; s >>= 1) {
        if (t < s) As[t] += As[t + s];
        __syncthreads();
      }
      if (t == 0) outp[66048] = As[0];
    }
    __syncthreads();                         // c_lds complete for stage C
  }

  // ================= Stage C: W1 partials (+ b1/W2 in dc==0 blocks) ======
  // total_W1[d][h] = sum_t xs[t][d] * c[t] * G[t][h]
  {
    const int dc = blk >> 4;        // 0..31, 8 d-rows each
    const int kc = blk & 15;        // 0..15, 128 t each
    const int d0 = dc * 8;
    const int t0 = kc * 128;
    const bool do_bw = (dc == 0);
    float acc[8] = {0.f, 0.f, 0.f, 0.f, 0.f, 0.f, 0.f, 0.f};
    float sb = 0.0f, sw = 0.0f;
#pragma unroll 4
    for (int tt = 0; tt < 128; ++tt) {
      const int t = t0 + tt;
      const float ct = c_lds[t];               // LDS broadcast
      const float gc = Gbuf[t * HH + j] * ct;  // coalesced
#pragma unroll
      for (int r = 0; r < 8; ++r)
        acc[r] = fmaf(gc, xs[t * DD + d0 + r], acc[r]);  // uniform -> s_load
      if (do_bw) {
        sb += gc;
        sw = fmaf(ct, Hbuf[t * HH + j], sw);
      }
    }
#pragma unroll
    for (int r = 0; r < 8; ++r)
      pW1[kc * 65536 + (d0 + r) * HH + j] = acc[r];
    if (do_bw) {
      pB1[kc * 256 + j] = sb;
      pW2[kc * 256 + j] = sw;
    }
  }

  grid.sync();

  // ================= Stage D: deterministic reductions ====================
  if (blk < 64) {
    const int i0 = blk * 1024 + j * 4;
    float4 sacc = make_float4(0.f, 0.f, 0.f, 0.f);
#pragma unroll
    for (int k = 0; k < 16; ++k) {
      const float4 v = *reinterpret_cast<const float4*>(pW1 + k * 65536 + i0);
      sacc.x += v.x; sacc.y += v.y; sacc.z += v.z; sacc.w += v.w;
    }
    *reinterpret_cast<float4*>(outp + i0) = sacc;          // total_W1
  } else if (blk == 64) {
    float sb = 0.0f, sw = 0.0f;
#pragma unroll
    for (int k = 0; k < 16; ++k) {
      sb += pB1[k * 256 + j];
      sw += pW2[k * 256 + j];
    }
    outp[65536 + j] = sb;        // total_b1
    outp[65792 + j] = sw;        // total_W2
  }
}

extern "C" void kernel_launch(void* const* d_in, const int* in_sizes, int n_in,
                              void* d_out, int out_size, void* d_ws, size_t ws_size,
                              hipStream_t stream) {
  const float* xs = (const float*)d_in[0];   // (2048, 256)
  const float* ys = (const float*)d_in[1];   // (2048, 2)
  const float* W1 = (const float*)d_in[2];   // (256, 256)
  const float* b1 = (const float*)d_in[3];   // (256,)
  const float* W2 = (const float*)d_in[4];   // (256, 1)
  const float* b2 = (const float*)d_in[5];   // (1,)
  float* outp = (float*)d_out;               // 66050 floats
  float* ws = (float*)d_ws;

  if (ws_size < (size_t)WS_FLOATS * sizeof(float)) return;  // loud fail

  float* Hbuf = ws + OFF_H;
  float* Gbuf = ws + OFF_G;
  float* ubuf = ws + OFF_U;
  float* pW1  = ws + OFF_PW1;
  float* pB1  = ws + OFF_PB1;
  float* pW2  = ws + OFF_PW2;

  void* args[] = {
      (void*)&xs, (void*)&ys, (void*)&W1, (void*)&b1, (void*)&W2, (void*)&b2,
      (void*)&Hbuf, (void*)&Gbuf, (void*)&ubuf,
      (void*)&pW1, (void*)&pB1, (void*)&pW2, (void*)&outp};

  hipLaunchCooperativeKernel((const void*)fused_kernel,
                             dim3(NBLK), dim3(NTHR), args, 0, stream);
}

// Round 3
// 90.086 us; speedup vs baseline: 2.0471x; 2.0471x over previous
//
#include <hip/hip_runtime.h>
#include <hip/hip_bf16.h>

#define TT 2048
#define DD 256
#define HH 256

#define GL_DECAY 0.891f        /* DISCOUNT * LAMBDA = 0.99*0.9 */
#define ALPHA    0.01f

// ---------------- workspace layout (floats) ----------------
#define OFF_H   0               /* Hbuf: T x H  = 524288 */
#define OFF_G   524288          /* Gbuf: T x H  = 524288 */
#define OFF_U   1048576         /* u: T = 2048 */
#define OFF_PW1 1050624         /* partW1: 8 x 65536 = 524288 */
#define OFF_PB1 1574912         /* partB1: 8 x 256 = 2048 */
#define OFF_PW2 1576960         /* partW2: 8 x 256 = 2048 */
#define WS_FLOATS 1579008       /* ~6.0 MB */

// ================= K1: forward =================
// 256 blocks x 512 threads. Block b -> rows [8b, 8b+8); half = tid>>8 owns 4 rows;
// j = tid&255 -> column j. A = xs@W1+b1; H = relu(A); G = (A>0)?W2:0; u = H@W2+b2.
__global__ __launch_bounds__(512) void fwd_kernel(
    const float* __restrict__ xs, const float* __restrict__ W1,
    const float* __restrict__ b1, const float* __restrict__ W2,
    const float* __restrict__ b2,
    float* __restrict__ Hbuf, float* __restrict__ Gbuf, float* __restrict__ u) {
  const int tid = threadIdx.x;
  const int j = tid & 255;
  const int half = tid >> 8;            // wave-uniform (256 = 4 waves)
  const int r0 = blockIdx.x * 8 + half * 4;
  __shared__ float red[8][256];         // 8 KB

  const float bj = b1[j];
  float acc[4] = {bj, bj, bj, bj};
  for (int k0 = 0; k0 < DD; k0 += 8) {
    float w[8];
#pragma unroll
    for (int kk = 0; kk < 8; ++kk)
      w[kk] = W1[(k0 + kk) * HH + j];           // coalesced, 8 in flight
#pragma unroll
    for (int r = 0; r < 4; ++r) {
#pragma unroll
      for (int kk = 0; kk < 8; ++kk)            // consecutive uniform -> s_load_dwordx8
        acc[r] = fmaf(xs[(r0 + r) * DD + k0 + kk], w[kk], acc[r]);
    }
  }
  const float w2j = W2[j];
#pragma unroll
  for (int r = 0; r < 4; ++r) {
    float a = acc[r];
    float h = fmaxf(a, 0.0f);
    float g = (a > 0.0f) ? w2j : 0.0f;
    Hbuf[(r0 + r) * HH + j] = h;
    Gbuf[(r0 + r) * HH + j] = g;
    red[half * 4 + r][j] = h * w2j;
  }
  __syncthreads();
  for (int s = 128; s >= 1; s >>= 1) {
    if (j < s) {
#pragma unroll
      for (int r = 0; r < 4; ++r)
        red[half * 4 + r][j] += red[half * 4 + r][j + s];
    }
    __syncthreads();
  }
  if (half == 0 && j < 8) u[blockIdx.x * 8 + j] = red[j][0] + b2[0];
}

// ================= K2: scans (replicated) + all partials =================
// 256 blocks x 512 threads. Every block recomputes the scalar scans (c -> LDS),
// then dc = blk>>3 (8 d-rows), kc = blk&7 (256 t, split across halves).
// dc==0 blocks also produce b1/W2 partials; block 0 writes b2 and sigma_last.
__global__ __launch_bounds__(512) void scan_w1_kernel(
    const float* __restrict__ u, const float* __restrict__ ys,
    const float* __restrict__ xs, const float* __restrict__ Gbuf,
    const float* __restrict__ Hbuf,
    float* __restrict__ pW1, float* __restrict__ pB1, float* __restrict__ pW2,
    float* __restrict__ outp) {
  const int tid = threadIdx.x;
  const int blk = blockIdx.x;
  __shared__ float c_lds[TT];           // 8 KB
  __shared__ float scr[2048];           // 8 KB: As/Bs then red

  // ---- scans: 512 segments x 4 steps ----
  {
    const int base = tid * 4;
    float e[4], keep[4];
#pragma unroll
    for (int i = 0; i < 4; ++i) {
      float g = ys[(base + i) * 2 + 0];
      float done = ys[(base + i) * 2 + 1];
      float d = g - u[base + i];
      e[i] = d * d;
      keep[i] = (done > 0.5f) ? 0.0f : 1.0f;
    }
    float A = 1.0f, B = 0.0f;
#pragma unroll
    for (int i = 0; i < 4; ++i) {
      float a = keep[i] * (1.0f - ALPHA);
      float b = keep[i] * (ALPHA * e[i]);
      A = a * A;
      B = a * B + b;
    }
    float* As = scr;
    float* Bs = scr + 512;
    As[tid] = A; Bs[tid] = B;
    __syncthreads();
    for (int s = 1; s < 512; s <<= 1) {         // inclusive scan L->R
      float pA = 1.0f, pB = 0.0f;
      if (tid >= s) { pA = As[tid - s]; pB = Bs[tid - s]; }
      __syncthreads();
      float nA = A * pA;
      float nB = A * pB + B;
      A = nA; B = nB;
      As[tid] = A; Bs[tid] = B;
      __syncthreads();
    }
    float r = (tid == 0) ? 0.0f : Bs[tid - 1];
    float sig[4];
#pragma unroll
    for (int i = 0; i < 4; ++i) {
      sig[i] = e[i] - r;
      float a = keep[i] * (1.0f - ALPHA);
      float b = keep[i] * (ALPHA * e[i]);
      r = a * r + b;
    }
    if (blk == 0 && tid == 511) outp[66049] = sig[3];   // sigmas[-1]

    float A2 = 1.0f, B2 = 0.0f;
#pragma unroll
    for (int i = 3; i >= 0; --i) {
      float a = GL_DECAY * keep[i];
      float nA = a * A2;
      float nB = a * B2 - sig[i];
      A2 = nA; B2 = nB;
    }
    __syncthreads();
    As[tid] = A2; Bs[tid] = B2;
    __syncthreads();
    for (int s = 1; s < 512; s <<= 1) {         // inclusive scan R->L
      float pA = 1.0f, pB = 0.0f;
      if (tid + s < 512) { pA = As[tid + s]; pB = Bs[tid + s]; }
      __syncthreads();
      float nA = A2 * pA;
      float nB = A2 * pB + B2;
      A2 = nA; B2 = nB;
      As[tid] = A2; Bs[tid] = B2;
      __syncthreads();
    }
    float cin = (tid == 511) ? 0.0f : Bs[tid + 1];
    float csum = 0.0f;
#pragma unroll
    for (int i = 3; i >= 0; --i) {
      float a = GL_DECAY * keep[i];
      cin = a * cin - sig[i];
      c_lds[base + i] = cin;
      csum += cin;
    }
    if (blk == 0) {                             // total_b2 = sum(c)
      __syncthreads();
      As[tid] = csum;
      __syncthreads();
      for (int s = 256; s >= 1; s >>= 1) {
        if (tid < s) As[tid] += As[tid + s];
        __syncthreads();
      }
      if (tid == 0) outp[66048] = As[0];
    }
    __syncthreads();                            // c_lds ready; scr reusable
  }

  // ---- W1 partials: total_W1[d][h] = sum_t xs[t][d]*c[t]*G[t][h] ----
  {
    const int j = tid & 255;
    const int half = tid >> 8;                  // wave-uniform
    const int dc = blk >> 3;                    // 0..31
    const int kc = blk & 7;                     // 0..7
    const int d0 = dc * 8;
    const int t0 = kc * 256 + half * 128;
    const bool do_bw = (dc == 0);
    float acc[8] = {0.f, 0.f, 0.f, 0.f, 0.f, 0.f, 0.f, 0.f};
    float sb = 0.0f, sw = 0.0f;
#pragma unroll 4
    for (int tt = 0; tt < 128; ++tt) {
      const int t = t0 + tt;
      const float ct = c_lds[t];                // LDS broadcast
      const float gc = Gbuf[t * HH + j] * ct;   // coalesced
#pragma unroll
      for (int r = 0; r < 8; ++r)               // consecutive uniform -> s_load_dwordx8
        acc[r] = fmaf(gc, xs[t * DD + d0 + r], acc[r]);
      if (do_bw) {
        sb += gc;
        sw = fmaf(ct, Hbuf[t * HH + j], sw);
      }
    }
    // combine halves via LDS, half 1 stores
    float (*red)[256] = (float (*)[256])scr;
    if (half == 0) {
#pragma unroll
      for (int r = 0; r < 8; ++r) red[r][j] = acc[r];
    }
    __syncthreads();
    if (half == 1) {
#pragma unroll
      for (int r = 0; r < 8; ++r)
        pW1[kc * 65536 + (d0 + r) * HH + j] = red[r][j] + acc[r];
    }
    if (do_bw) {                                // dc uniform per block
      __syncthreads();
      if (half == 0) { red[0][j] = sb; red[1][j] = sw; }
      __syncthreads();
      if (half == 1) {
        pB1[kc * 256 + j] = red[0][j] + sb;
        pW2[kc * 256 + j] = red[1][j] + sw;
      }
    }
  }
}

// ================= K3: deterministic reductions =================
// blocks 0..63: W1 (8 partials, float4). block 64: b1 / W2 (8 partials each).
__global__ __launch_bounds__(256) void reduce_kernel(
    const float* __restrict__ pW1, const float* __restrict__ pB1,
    const float* __restrict__ pW2, float* __restrict__ outp) {
  if (blockIdx.x < 64) {
    const int i0 = blockIdx.x * 1024 + threadIdx.x * 4;
    float4 sacc = make_float4(0.f, 0.f, 0.f, 0.f);
#pragma unroll
    for (int k = 0; k < 8; ++k) {
      const float4 v = *reinterpret_cast<const float4*>(pW1 + k * 65536 + i0);
      sacc.x += v.x; sacc.y += v.y; sacc.z += v.z; sacc.w += v.w;
    }
    *reinterpret_cast<float4*>(outp + i0) = sacc;          // total_W1
  } else {
    const int j = threadIdx.x;
    float sb = 0.0f, sw = 0.0f;
#pragma unroll
    for (int k = 0; k < 8; ++k) {
      sb += pB1[k * 256 + j];
      sw += pW2[k * 256 + j];
    }
    outp[65536 + j] = sb;        // total_b1
    outp[65792 + j] = sw;        // total_W2
  }
}

extern "C" void kernel_launch(void* const* d_in, const int* in_sizes, int n_in,
                              void* d_out, int out_size, void* d_ws, size_t ws_size,
                              hipStream_t stream) {
  const float* xs = (const float*)d_in[0];   // (2048, 256)
  const float* ys = (const float*)d_in[1];   // (2048, 2)
  const float* W1 = (const float*)d_in[2];   // (256, 256)
  const float* b1 = (const float*)d_in[3];   // (256,)
  const float* W2 = (const float*)d_in[4];   // (256, 1)
  const float* b2 = (const float*)d_in[5];   // (1,)
  float* outp = (float*)d_out;               // 66050 floats
  float* ws = (float*)d_ws;

  if (ws_size < (size_t)WS_FLOATS * sizeof(float)) return;  // loud fail

  float* Hbuf = ws + OFF_H;
  float* Gbuf = ws + OFF_G;
  float* ubuf = ws + OFF_U;
  float* pW1  = ws + OFF_PW1;
  float* pB1  = ws + OFF_PB1;
  float* pW2  = ws + OFF_PW2;

  fwd_kernel<<<256, 512, 0, stream>>>(xs, W1, b1, W2, b2, Hbuf, Gbuf, ubuf);
  scan_w1_kernel<<<256, 512, 0, stream>>>(ubuf, ys, xs, Gbuf, Hbuf,
                                          pW1, pB1, pW2, outp);
  reduce_kernel<<<65, 256, 0, stream>>>(pW1, pB1, pW2, outp);
}

// Round 4
// 75.305 us; speedup vs baseline: 2.4489x; 1.1963x over previous
//
#include <hip/hip_runtime.h>
#include <hip/hip_bf16.h>

#define TT 2048
#define DDIM 256
#define HHDIM 256

#define GL  0.891f      /* DISCOUNT*LAMBDA */
#define OMA 0.99f       /* 1 - alpha */
#define AL  0.01f       /* alpha */

// ---------------- workspace layout (floats) ----------------
#define OFF_H   0               /* Hbuf: T x H = 524288 */
#define OFF_G   524288          /* Gbuf: T x H = 524288 */
#define OFF_U   1048576         /* u: T = 2048 */
#define OFF_PW1 1050624         /* partW1: 8 x 65536 */
#define OFF_PB1 1574912         /* partB1: 8 x 256 */
#define OFF_PW2 1576960         /* partW2: 8 x 256 */
#define WS_FLOATS 1579008

// ================= K1: forward =================
// 256 blocks x 512 threads; block owns rows [8b, 8b+8).
// xs rows staged in LDS (broadcast reads); W1 coalesced per-lane; halves split k.
__global__ __launch_bounds__(512) void fwd_kernel(
    const float* __restrict__ xs, const float* __restrict__ W1,
    const float* __restrict__ b1, const float* __restrict__ W2,
    const float* __restrict__ b2,
    float* __restrict__ Hbuf, float* __restrict__ Gbuf, float* __restrict__ u) {
  const int tid = threadIdx.x;
  const int j = tid & 255;
  const int half = tid >> 8;            // wave-uniform
  const int r0 = blockIdx.x * 8;
  __shared__ float xsl[8 * 260];        // [r][k], row pad 260 (16B-aligned rows)
  __shared__ float red[8][256];

  {  // stage xs[8][256] -> LDS, coalesced float4
    const int row = tid >> 6;
    const int k0 = (tid & 63) * 4;
    float4 v = *reinterpret_cast<const float4*>(&xs[(r0 + row) * DDIM + k0]);
    *reinterpret_cast<float4*>(&xsl[row * 260 + k0]) = v;
  }
  __syncthreads();

  float acc[8] = {0.f, 0.f, 0.f, 0.f, 0.f, 0.f, 0.f, 0.f};
  const int kb = half * 128;
#pragma unroll 2
  for (int kk = 0; kk < 128; kk += 4) {
    const int k = kb + kk;
    const float w0 = W1[(k + 0) * HHDIM + j];   // coalesced
    const float w1 = W1[(k + 1) * HHDIM + j];
    const float w2 = W1[(k + 2) * HHDIM + j];
    const float w3 = W1[(k + 3) * HHDIM + j];
#pragma unroll
    for (int r = 0; r < 8; ++r) {
      const float4 xv = *reinterpret_cast<const float4*>(&xsl[r * 260 + k]);  // broadcast b128
      acc[r] = fmaf(xv.x, w0, acc[r]);
      acc[r] = fmaf(xv.y, w1, acc[r]);
      acc[r] = fmaf(xv.z, w2, acc[r]);
      acc[r] = fmaf(xv.w, w3, acc[r]);
    }
  }
  if (half == 0) {
#pragma unroll
    for (int r = 0; r < 8; ++r) red[r][j] = acc[r];
  }
  __syncthreads();
  if (half == 1) {
    const float bj = b1[j];
    const float w2j = W2[j];
#pragma unroll
    for (int r = 0; r < 8; ++r) {
      const float a = red[r][j] + acc[r] + bj;
      const float h = fmaxf(a, 0.f);
      const float g = (a > 0.f) ? w2j : 0.f;
      Hbuf[(r0 + r) * HHDIM + j] = h;
      Gbuf[(r0 + r) * HHDIM + j] = g;
      red[r][j] = h * w2j;               // same-thread read->write, safe
    }
  }
  __syncthreads();
  for (int s = 128; s >= 1; s >>= 1) {   // rows reduced over j; halves take 4 rows each
    if (j < s) {
#pragma unroll
      for (int rr = 0; rr < 4; ++rr)
        red[half * 4 + rr][j] += red[half * 4 + rr][j + s];
    }
    __syncthreads();
  }
  if (half == 0 && j < 8) u[r0 + j] = red[j][0] + b2[0];
}

// ================= K2: wave0-scan + W1/b1/W2 partials =================
// 256 blocks x 512 threads; dc = blk>>3 (8 d-rows), kc = blk&7 (256 t).
// Wave 0 does the full forward/backward affine scans in-register via shfl,
// using lane-permuted LDS (perm(t) = (t&31)*64 + (t>>5)) for conflict-free
// strided access. c stays in LDS (perm layout) for the GEMM phase.
__global__ __launch_bounds__(512) void scan_w1_kernel(
    const float* __restrict__ u, const float* __restrict__ ys,
    const float* __restrict__ xs, const float* __restrict__ Gbuf,
    const float* __restrict__ Hbuf,
    float* __restrict__ pW1, float* __restrict__ pB1, float* __restrict__ pW2,
    float* __restrict__ outp) {
  const int tid = threadIdx.x;
  const int blk = blockIdx.x;
  const int j = tid & 255;
  const int half = tid >> 8;            // wave-uniform
  const int dc = blk >> 3;              // 0..31
  const int kc = blk & 7;               // 0..7
  const int d0 = dc * 8;
  const int tb = kc * 256;

  __shared__ float LDS[8192];           // 32 KB
  float2* ek = (float2*)LDS;            // words [0,4096): (e,keep) perm layout
  float* c_l = LDS + 4096;              // words [4096,6144): c, perm layout
  float* xt = LDS + 6144;               // words [6144,8192): xs tile [256][8]

  // ---- phase 0: build ek (all threads, 4 t each) + stage xs tile ----
  {
    const float4 u4 = ((const float4*)u)[tid];
    const float4 y0 = ((const float4*)ys)[2 * tid];      // g0,d0,g1,d1
    const float4 y1 = ((const float4*)ys)[2 * tid + 1];  // g2,d2,g3,d3
    float e0 = y0.x - u4.x; e0 *= e0;
    float e1 = y0.z - u4.y; e1 *= e1;
    float e2 = y1.x - u4.z; e2 *= e2;
    float e3 = y1.z - u4.w; e3 *= e3;
    const float k0 = (y0.y > 0.5f) ? 0.f : 1.f;
    const float k1 = (y0.w > 0.5f) ? 0.f : 1.f;
    const float k2 = (y1.y > 0.5f) ? 0.f : 1.f;
    const float k3 = (y1.w > 0.5f) ? 0.f : 1.f;
    const int lo = (4 * tid) & 31;      // +i never crosses 32
    const int hi = tid >> 3;
    ek[(lo + 0) * 64 + hi] = make_float2(e0, k0);
    ek[(lo + 1) * 64 + hi] = make_float2(e1, k1);
    ek[(lo + 2) * 64 + hi] = make_float2(e2, k2);
    ek[(lo + 3) * 64 + hi] = make_float2(e3, k3);
  }
  {
    const int tt = tid >> 1, q = tid & 1;
    float4 v = *reinterpret_cast<const float4*>(&xs[(tb + tt) * DDIM + d0 + 4 * q]);
    *reinterpret_cast<float4*>(&xt[tt * 8 + 4 * q]) = v;
  }
  __syncthreads();

  // ---- phase 1: wave 0 scans; lane l owns t in [32l, 32l+32) ----
  if (tid < 64) {
    const int l = tid;
    // forward compose: r' = a*r + b, a = keep*(1-al), b = keep*(al*e)
    float A = 1.f, B = 0.f;
#pragma unroll
    for (int i = 0; i < 32; ++i) {
      const float2 v = ek[i * 64 + l];
      const float a = v.y * OMA;
      B = fmaf(a, B, v.y * (AL * v.x));
      A *= a;
    }
#pragma unroll
    for (int s = 1; s < 64; s <<= 1) {  // inclusive wave scan (prev applied first)
      const float pA = __shfl_up(A, s, 64);
      const float pB = __shfl_up(B, s, 64);
      if (l >= s) { B = fmaf(A, pB, B); A *= pA; }
    }
    float r = __shfl_up(B, 1, 64);      // exclusive: r entering segment (r0 = 0)
    if (l == 0) r = 0.f;
    float lastsig = 0.f;
#pragma unroll
    for (int i = 0; i < 32; ++i) {      // sigma pass; sig overwrites e slot
      const float2 v = ek[i * 64 + l];
      const float sig = v.x - r;
      ek[i * 64 + l].x = sig;
      const float a = v.y * OMA;
      r = fmaf(a, r, v.y * (AL * v.x));
      if (i == 31) lastsig = sig;
    }
    // backward compose: c_t = GL*keep_t*c_{t+1} - sig_t (right-to-left)
    float A2 = 1.f, B2 = 0.f;
#pragma unroll
    for (int i = 31; i >= 0; --i) {
      const float2 v = ek[i * 64 + l];  // (sig, keep)
      const float a = GL * v.y;
      B2 = fmaf(a, B2, -v.x);
      A2 *= a;
    }
#pragma unroll
    for (int s = 1; s < 64; s <<= 1) {  // suffix inclusive scan (next applied first)
      const float nA = __shfl_down(A2, s, 64);
      const float nB = __shfl_down(B2, s, 64);
      if (l + s < 64) { B2 = fmaf(A2, nB, B2); A2 *= nA; }
    }
    float cin = __shfl_down(B2, 1, 64); // c entering from the right (c_T = 0)
    if (l == 63) cin = 0.f;
    float csum = 0.f;
#pragma unroll
    for (int i = 31; i >= 0; --i) {
      const float2 v = ek[i * 64 + l];
      cin = fmaf(GL * v.y, cin, -v.x);
      c_l[i * 64 + l] = cin;            // perm layout, conflict-free
      csum += cin;
    }
#pragma unroll
    for (int s = 32; s >= 1; s >>= 1) csum += __shfl_xor(csum, s, 64);
    if (blk == 0) {
      if (l == 0) outp[66048] = csum;       // total_b2
      if (l == 63) outp[66049] = lastsig;   // sigmas[-1]
    }
  }
  __syncthreads();

  // ---- phase 2: W1 partials (+ b1/W2 for dc==0) ----
  const int th0 = tb + half * 128;
  float acc[8] = {0.f, 0.f, 0.f, 0.f, 0.f, 0.f, 0.f, 0.f};
  float sb = 0.f, sw = 0.f;
  const bool do_bw = (dc == 0);
#pragma unroll 4
  for (int tt = 0; tt < 128; ++tt) {
    const int t = th0 + tt;
    const float ct = c_l[((t & 31) << 6) + (t >> 5)];   // broadcast
    const float g = Gbuf[t * HHDIM + j];                // coalesced
    const float gc = g * ct;
    const int tl = half * 128 + tt;
    const float4 x0 = *reinterpret_cast<const float4*>(&xt[tl * 8]);      // broadcast b128
    const float4 x1 = *reinterpret_cast<const float4*>(&xt[tl * 8 + 4]);
    acc[0] = fmaf(gc, x0.x, acc[0]);
    acc[1] = fmaf(gc, x0.y, acc[1]);
    acc[2] = fmaf(gc, x0.z, acc[2]);
    acc[3] = fmaf(gc, x0.w, acc[3]);
    acc[4] = fmaf(gc, x1.x, acc[4]);
    acc[5] = fmaf(gc, x1.y, acc[5]);
    acc[6] = fmaf(gc, x1.z, acc[6]);
    acc[7] = fmaf(gc, x1.w, acc[7]);
    if (do_bw) {
      sb += gc;
      sw = fmaf(ct, Hbuf[t * HHDIM + j], sw);
    }
  }
  // combine halves via LDS (red overlays ek words [0,2048) — dead after phase 1)
  float (*red)[256] = (float (*)[256])LDS;
  if (half == 0) {
#pragma unroll
    for (int r = 0; r < 8; ++r) red[r][j] = acc[r];
  }
  __syncthreads();
  if (half == 1) {
#pragma unroll
    for (int r = 0; r < 8; ++r)
      pW1[kc * 65536 + (d0 + r) * HHDIM + j] = red[r][j] + acc[r];
  }
  if (do_bw) {                           // block-uniform branch
    __syncthreads();
    if (half == 0) { red[0][j] = sb; red[1][j] = sw; }
    __syncthreads();
    if (half == 1) {
      pB1[kc * 256 + j] = red[0][j] + sb;
      pW2[kc * 256 + j] = red[1][j] + sw;
    }
  }
}

// ================= K3: deterministic reductions =================
__global__ __launch_bounds__(256) void reduce_kernel(
    const float* __restrict__ pW1, const float* __restrict__ pB1,
    const float* __restrict__ pW2, float* __restrict__ outp) {
  if (blockIdx.x < 64) {
    const int i0 = blockIdx.x * 1024 + threadIdx.x * 4;
    float4 sacc = make_float4(0.f, 0.f, 0.f, 0.f);
#pragma unroll
    for (int k = 0; k < 8; ++k) {
      const float4 v = *reinterpret_cast<const float4*>(pW1 + k * 65536 + i0);
      sacc.x += v.x; sacc.y += v.y; sacc.z += v.z; sacc.w += v.w;
    }
    *reinterpret_cast<float4*>(outp + i0) = sacc;          // total_W1
  } else {
    const int j = threadIdx.x;
    float sb = 0.f, sw = 0.f;
#pragma unroll
    for (int k = 0; k < 8; ++k) {
      sb += pB1[k * 256 + j];
      sw += pW2[k * 256 + j];
    }
    outp[65536 + j] = sb;        // total_b1
    outp[65792 + j] = sw;        // total_W2
  }
}

extern "C" void kernel_launch(void* const* d_in, const int* in_sizes, int n_in,
                              void* d_out, int out_size, void* d_ws, size_t ws_size,
                              hipStream_t stream) {
  const float* xs = (const float*)d_in[0];   // (2048, 256)
  const float* ys = (const float*)d_in[1];   // (2048, 2)
  const float* W1 = (const float*)d_in[2];   // (256, 256)
  const float* b1 = (const float*)d_in[3];   // (256,)
  const float* W2 = (const float*)d_in[4];   // (256, 1)
  const float* b2 = (const float*)d_in[5];   // (1,)
  float* outp = (float*)d_out;               // 66050 floats
  float* ws = (float*)d_ws;

  if (ws_size < (size_t)WS_FLOATS * sizeof(float)) return;  // loud fail

  float* Hbuf = ws + OFF_H;
  float* Gbuf = ws + OFF_G;
  float* ubuf = ws + OFF_U;
  float* pW1  = ws + OFF_PW1;
  float* pB1  = ws + OFF_PB1;
  float* pW2  = ws + OFF_PW2;

  fwd_kernel<<<256, 512, 0, stream>>>(xs, W1, b1, W2, b2, Hbuf, Gbuf, ubuf);
  scan_w1_kernel<<<256, 512, 0, stream>>>(ubuf, ys, xs, Gbuf, Hbuf,
                                          pW1, pB1, pW2, outp);
  reduce_kernel<<<65, 256, 0, stream>>>(pW1, pB1, pW2, outp);
}

// Round 5
// 35.041 us; speedup vs baseline: 5.2628x; 2.1491x over previous
//
#include <hip/hip_runtime.h>

#define GL  0.891f      /* DISCOUNT*LAMBDA */
#define OMA 0.99f       /* 1 - alpha */
#define AL  0.01f       /* alpha */

// ---------------- workspace layout (floats) ----------------
#define OFF_H   0               /* Hbuf: T x H = 524288 */
#define OFF_G   524288          /* Gbuf: T x H = 524288 */
#define OFF_U   1048576         /* u: T = 2048 */
#define OFF_PW1 1050624         /* partW1: 32 x 65536 = 2097152 */
#define OFF_PB1 3147776         /* partB1: 32 x 256 */
#define OFF_PW2 3155968         /* partW2: 32 x 256 */
#define WS_FLOATS 3164160       /* ~12.1 MB */

// ================= K1: forward =================
// 256 blocks x 512 threads; block owns rows [8b, 8b+8); halves split k.
// W1 loads batched x8 (one vm-wait per batch); xs rows broadcast from LDS.
__global__ __launch_bounds__(512, 2) void fwd_kernel(
    const float* __restrict__ xs, const float* __restrict__ W1,
    const float* __restrict__ b1, const float* __restrict__ W2,
    const float* __restrict__ b2,
    float* __restrict__ Hbuf, float* __restrict__ Gbuf, float* __restrict__ u) {
  const int tid = threadIdx.x;
  const int j = tid & 255;
  const int half = tid >> 8;            // wave-uniform
  const int r0 = blockIdx.x * 8;
  __shared__ __align__(16) float xsl[8 * 260];   // [r][k], padded rows
  __shared__ __align__(16) float red[8][256];

  {  // stage xs[8][256] -> LDS, coalesced float4
    const int row = tid >> 6;
    const int k0 = (tid & 63) * 4;
    float4 v = *reinterpret_cast<const float4*>(&xs[(r0 + row) * 256 + k0]);
    *reinterpret_cast<float4*>(&xsl[row * 260 + k0]) = v;
  }
  __syncthreads();

  float acc[8] = {0.f, 0.f, 0.f, 0.f, 0.f, 0.f, 0.f, 0.f};
  const int kb = half * 128;
  for (int k0 = 0; k0 < 128; k0 += 8) {
    const int k = kb + k0;
    float w[8];
#pragma unroll
    for (int kk = 0; kk < 8; ++kk)
      w[kk] = W1[(k + kk) * 256 + j];            // 8 coalesced loads in flight
#pragma unroll
    for (int r = 0; r < 8; ++r) {
      const float4 xa = *reinterpret_cast<const float4*>(&xsl[r * 260 + k]);
      const float4 xb = *reinterpret_cast<const float4*>(&xsl[r * 260 + k + 4]);
      acc[r] = fmaf(xa.x, w[0], acc[r]);
      acc[r] = fmaf(xa.y, w[1], acc[r]);
      acc[r] = fmaf(xa.z, w[2], acc[r]);
      acc[r] = fmaf(xa.w, w[3], acc[r]);
      acc[r] = fmaf(xb.x, w[4], acc[r]);
      acc[r] = fmaf(xb.y, w[5], acc[r]);
      acc[r] = fmaf(xb.z, w[6], acc[r]);
      acc[r] = fmaf(xb.w, w[7], acc[r]);
    }
  }
  if (half == 0) {
#pragma unroll
    for (int r = 0; r < 8; ++r) red[r][j] = acc[r];
  }
  __syncthreads();
  if (half == 1) {
    const float bj = b1[j];
    const float w2j = W2[j];
#pragma unroll
    for (int r = 0; r < 8; ++r) {
      const float a = red[r][j] + acc[r] + bj;
      const float h = fmaxf(a, 0.f);
      const float g = (a > 0.f) ? w2j : 0.f;
      Hbuf[(r0 + r) * 256 + j] = h;
      Gbuf[(r0 + r) * 256 + j] = g;
      red[r][j] = h * w2j;               // same-thread read->write, safe
    }
  }
  __syncthreads();
  for (int s = 128; s >= 1; s >>= 1) {
    if (j < s) {
#pragma unroll
      for (int rr = 0; rr < 4; ++rr)
        red[half * 4 + rr][j] += red[half * 4 + rr][j + s];
    }
    __syncthreads();
  }
  if (half == 0 && j < 8) u[r0 + j] = red[j][0] + b2[0];
}

// ================= K2: all-wave scan + W1/b1/W2 partials =================
// 256 blocks x 256 threads; dc = blk>>5 (32 d-rows), kc = blk&31 (64 t).
// Scan: per-thread 8-elem affine compose -> wave shfl scan -> 4-aggregate
// exchange via LDS. All state in registers; c -> LDS natural layout.
// Phase 2: G loads batched x16 (one vm-wait per 16), 32 FMA per t from LDS.
__global__ __launch_bounds__(256, 4) void scan_w1_kernel(
    const float* __restrict__ u, const float* __restrict__ ys,
    const float* __restrict__ xs, const float* __restrict__ Gbuf,
    const float* __restrict__ Hbuf,
    float* __restrict__ pW1, float* __restrict__ pB1, float* __restrict__ pW2,
    float* __restrict__ outp) {
  const int tid = threadIdx.x;
  const int blk = blockIdx.x;
  const int dc = blk >> 5;              // 0..7
  const int kc = blk & 31;              // 0..31
  const int d0 = dc * 32;
  const int tb = kc * 64;
  const int lane = tid & 63;
  const int w = tid >> 6;               // wave id 0..3

  __shared__ __align__(16) float c_l[2048];     // 8 KB
  __shared__ __align__(16) float xt[64 * 32];   // 8 KB: xs[tb+t][d0..d0+32]
  __shared__ float aggA[4], aggB[4], ag2A[4], ag2B[4], wsum[4];

  // ---- stage xs tile (coalesced float4, 2 per thread) ----
#pragma unroll
  for (int q = 0; q < 2; ++q) {
    const int idx = tid * 2 + q;        // 0..511
    const int row = idx >> 3;           // 0..63
    const int qd = idx & 7;             // 8 quads per 32-float row
    *reinterpret_cast<float4*>(&xt[row * 32 + qd * 4]) =
        *reinterpret_cast<const float4*>(&xs[(tb + row) * 256 + d0 + qd * 4]);
  }

  // ---- scan: thread owns t in [8*tid, 8*tid+8) ----
  float e[8], kp[8];
  {
    const float4 ua = ((const float4*)u)[2 * tid];
    const float4 ub = ((const float4*)u)[2 * tid + 1];
    const float uu[8] = {ua.x, ua.y, ua.z, ua.w, ub.x, ub.y, ub.z, ub.w};
#pragma unroll
    for (int q = 0; q < 4; ++q) {
      const float4 y = ((const float4*)ys)[4 * tid + q];  // g,done,g,done
      float da = y.x - uu[2 * q];
      float db = y.z - uu[2 * q + 1];
      e[2 * q] = da * da;
      e[2 * q + 1] = db * db;
      kp[2 * q] = (y.y > 0.5f) ? 0.f : 1.f;
      kp[2 * q + 1] = (y.w > 0.5f) ? 0.f : 1.f;
    }
  }
  // forward: r' = a r + b, a = kp*OMA, b = kp*AL*e
  float A = 1.f, B = 0.f;
#pragma unroll
  for (int i = 0; i < 8; ++i) {
    const float a = kp[i] * OMA;
    B = fmaf(a, B, kp[i] * (AL * e[i]));
    A *= a;
  }
#pragma unroll
  for (int s = 1; s < 64; s <<= 1) {    // wave inclusive scan
    const float pA = __shfl_up(A, s, 64);
    const float pB = __shfl_up(B, s, 64);
    if (lane >= s) { B = fmaf(A, pB, B); A *= pA; }
  }
  if (lane == 63) { aggA[w] = A; aggB[w] = B; }
  __syncthreads();
  float rin;
  {
    float rw = 0.f;                     // r entering this wave (r0 = 0)
    for (int v = 0; v < w; ++v) rw = fmaf(aggA[v], rw, aggB[v]);
    float lA = __shfl_up(A, 1, 64);     // lane-exclusive prefix
    float lB = __shfl_up(B, 1, 64);
    if (lane == 0) { lA = 1.f; lB = 0.f; }
    rin = fmaf(lA, rw, lB);
  }
  float sig[8];
  {
    float r = rin;
#pragma unroll
    for (int i = 0; i < 8; ++i) {
      sig[i] = e[i] - r;
      const float a = kp[i] * OMA;
      r = fmaf(a, r, kp[i] * (AL * e[i]));
    }
  }
  if (blk == 0 && tid == 255) outp[66049] = sig[7];   // sigmas[-1]

  // backward: c_t = GL*kp_t*c_{t+1} - sig_t
  float A2 = 1.f, B2 = 0.f;
#pragma unroll
  for (int i = 7; i >= 0; --i) {
    const float a = GL * kp[i];
    B2 = fmaf(a, B2, -sig[i]);
    A2 *= a;
  }
#pragma unroll
  for (int s = 1; s < 64; s <<= 1) {    // wave suffix-inclusive scan
    const float nA = __shfl_down(A2, s, 64);
    const float nB = __shfl_down(B2, s, 64);
    if (lane + s < 64) { B2 = fmaf(A2, nB, B2); A2 *= nA; }
  }
  if (lane == 0) { ag2A[w] = A2; ag2B[w] = B2; }
  __syncthreads();
  float cin;
  {
    float cw = 0.f;                     // c entering this wave from the right
    for (int v = 3; v > w; --v) cw = fmaf(ag2A[v], cw, ag2B[v]);
    float lA = __shfl_down(A2, 1, 64);  // lane-exclusive suffix
    float lB = __shfl_down(B2, 1, 64);
    if (lane == 63) { lA = 1.f; lB = 0.f; }
    cin = fmaf(lA, cw, lB);
  }
  float cr[8];
  float cc = cin, csum = 0.f;
#pragma unroll
  for (int i = 7; i >= 0; --i) {
    cc = fmaf(GL * kp[i], cc, -sig[i]);
    cr[i] = cc;
    csum += cc;
  }
  *reinterpret_cast<float4*>(&c_l[8 * tid]) = make_float4(cr[0], cr[1], cr[2], cr[3]);
  *reinterpret_cast<float4*>(&c_l[8 * tid + 4]) = make_float4(cr[4], cr[5], cr[6], cr[7]);
  if (blk == 0) {
#pragma unroll
    for (int s = 32; s >= 1; s >>= 1) csum += __shfl_xor(csum, s, 64);
    if (lane == 0) wsum[w] = csum;
  }
  __syncthreads();                      // c_l (+ wsum) ready
  if (blk == 0 && tid == 0)
    outp[66048] = wsum[0] + wsum[1] + wsum[2] + wsum[3];   // total_b2

  // ---- phase 2: W1 partials (+ b1/W2 for dc==0) ----
  const int j = tid;
  float acc[32];
#pragma unroll
  for (int r = 0; r < 32; ++r) acc[r] = 0.f;

  if (dc != 0) {
    for (int t0 = 0; t0 < 64; t0 += 16) {
      float g[16];
#pragma unroll
      for (int i = 0; i < 16; ++i)
        g[i] = Gbuf[(tb + t0 + i) * 256 + j];   // 16 loads in flight
#pragma unroll
      for (int i = 0; i < 16; ++i) {
        const int tl = t0 + i;
        const float gc = g[i] * c_l[tb + tl];
#pragma unroll
        for (int q = 0; q < 8; ++q) {
          const float4 xv = *reinterpret_cast<const float4*>(&xt[tl * 32 + 4 * q]);
          acc[4 * q + 0] = fmaf(gc, xv.x, acc[4 * q + 0]);
          acc[4 * q + 1] = fmaf(gc, xv.y, acc[4 * q + 1]);
          acc[4 * q + 2] = fmaf(gc, xv.z, acc[4 * q + 2]);
          acc[4 * q + 3] = fmaf(gc, xv.w, acc[4 * q + 3]);
        }
      }
    }
  } else {
    float sb = 0.f, sw = 0.f;
    for (int t0 = 0; t0 < 64; t0 += 16) {
      float g[16], h[16];
#pragma unroll
      for (int i = 0; i < 16; ++i)
        g[i] = Gbuf[(tb + t0 + i) * 256 + j];
#pragma unroll
      for (int i = 0; i < 16; ++i)
        h[i] = Hbuf[(tb + t0 + i) * 256 + j];
#pragma unroll
      for (int i = 0; i < 16; ++i) {
        const int tl = t0 + i;
        const float ct = c_l[tb + tl];
        const float gc = g[i] * ct;
#pragma unroll
        for (int q = 0; q < 8; ++q) {
          const float4 xv = *reinterpret_cast<const float4*>(&xt[tl * 32 + 4 * q]);
          acc[4 * q + 0] = fmaf(gc, xv.x, acc[4 * q + 0]);
          acc[4 * q + 1] = fmaf(gc, xv.y, acc[4 * q + 1]);
          acc[4 * q + 2] = fmaf(gc, xv.z, acc[4 * q + 2]);
          acc[4 * q + 3] = fmaf(gc, xv.w, acc[4 * q + 3]);
        }
        sb += gc;
        sw = fmaf(ct, h[i], sw);
      }
    }
    pB1[kc * 256 + j] = sb;
    pW2[kc * 256 + j] = sw;
  }
#pragma unroll
  for (int r = 0; r < 32; ++r)
    pW1[kc * 65536 + (d0 + r) * 256 + j] = acc[r];
}

// ================= K3: deterministic reductions =================
// blocks 0..255: W1 columns (256 floats each, 32 partials). block 256: b1/W2.
__global__ __launch_bounds__(256) void reduce_kernel(
    const float* __restrict__ pW1, const float* __restrict__ pB1,
    const float* __restrict__ pW2, float* __restrict__ outp) {
  if (blockIdx.x < 256) {
    const int col = blockIdx.x * 256 + threadIdx.x;
    float s = 0.f;
#pragma unroll 8
    for (int k = 0; k < 32; ++k) s += pW1[k * 65536 + col];
    outp[col] = s;                       // total_W1
  } else {
    const int j = threadIdx.x;
    float sb = 0.f, sw = 0.f;
#pragma unroll 8
    for (int k = 0; k < 32; ++k) {
      sb += pB1[k * 256 + j];
      sw += pW2[k * 256 + j];
    }
    outp[65536 + j] = sb;                // total_b1
    outp[65792 + j] = sw;                // total_W2
  }
}

extern "C" void kernel_launch(void* const* d_in, const int* in_sizes, int n_in,
                              void* d_out, int out_size, void* d_ws, size_t ws_size,
                              hipStream_t stream) {
  const float* xs = (const float*)d_in[0];   // (2048, 256)
  const float* ys = (const float*)d_in[1];   // (2048, 2)
  const float* W1 = (const float*)d_in[2];   // (256, 256)
  const float* b1 = (const float*)d_in[3];   // (256,)
  const float* W2 = (const float*)d_in[4];   // (256, 1)
  const float* b2 = (const float*)d_in[5];   // (1,)
  float* outp = (float*)d_out;               // 66050 floats
  float* ws = (float*)d_ws;

  if (ws_size < (size_t)WS_FLOATS * sizeof(float)) return;  // loud fail

  float* Hbuf = ws + OFF_H;
  float* Gbuf = ws + OFF_G;
  float* ubuf = ws + OFF_U;
  float* pW1  = ws + OFF_PW1;
  float* pB1  = ws + OFF_PB1;
  float* pW2  = ws + OFF_PW2;

  fwd_kernel<<<256, 512, 0, stream>>>(xs, W1, b1, W2, b2, Hbuf, Gbuf, ubuf);
  scan_w1_kernel<<<256, 256, 0, stream>>>(ubuf, ys, xs, Gbuf, Hbuf,
                                          pW1, pB1, pW2, outp);
  reduce_kernel<<<257, 256, 0, stream>>>(pW1, pB1, pW2, outp);
}

// Round 6
// 33.391 us; speedup vs baseline: 5.5229x; 1.0494x over previous
//
#include <hip/hip_runtime.h>

#define GL  0.891f      /* DISCOUNT*LAMBDA */
#define OMA 0.99f       /* 1 - alpha */
#define AL  0.01f       /* alpha */

// ---------------- workspace layout (floats) ----------------
#define OFF_H   0               /* Hbuf: T x H = 524288 */
#define OFF_U   524288          /* u: T = 2048 */
#define OFF_PW1 526336          /* partW1: 32 x 65536 = 2097152 */
#define OFF_PB1 2623488         /* partB1: 32 x 256 */
#define OFF_PW2 2631680         /* partW2: 32 x 256 */
#define WS_FLOATS 2639872       /* ~10.1 MB */

// ================= K1: forward =================
// 256 blocks x 512 threads; block owns rows [8b, 8b+8); halves split k (128 each).
// W1 loads: k-batches of 16, double-buffered, batch0 issued before the barrier.
__global__ __launch_bounds__(512, 2) void fwd_kernel(
    const float* __restrict__ xs, const float* __restrict__ W1,
    const float* __restrict__ b1, const float* __restrict__ W2,
    const float* __restrict__ b2,
    float* __restrict__ Hbuf, float* __restrict__ u) {
  const int tid = threadIdx.x;
  const int j = tid & 255;
  const int half = tid >> 8;            // wave-uniform
  const int r0 = blockIdx.x * 8;
  __shared__ __align__(16) float xsl[8 * 260];   // [r][k], padded rows
  __shared__ __align__(16) float red[8][256];

  {  // stage xs[8][256] -> LDS, coalesced float4
    const int row = tid >> 6;
    const int k0 = (tid & 63) * 4;
    float4 v = *reinterpret_cast<const float4*>(&xs[(r0 + row) * 256 + k0]);
    *reinterpret_cast<float4*>(&xsl[row * 260 + k0]) = v;
  }

  const int kb = half * 128;
  float wcur[16], wnxt[16];
#pragma unroll
  for (int kk = 0; kk < 16; ++kk)       // batch 0 in flight before barrier
    wcur[kk] = W1[(kb + kk) * 256 + j];
  __syncthreads();

  float acc[8] = {0.f, 0.f, 0.f, 0.f, 0.f, 0.f, 0.f, 0.f};
#pragma unroll
  for (int b = 0; b < 8; ++b) {
    if (b < 7) {
#pragma unroll
      for (int kk = 0; kk < 16; ++kk)
        wnxt[kk] = W1[(kb + (b + 1) * 16 + kk) * 256 + j];
    }
    const int k = kb + b * 16;
#pragma unroll
    for (int r = 0; r < 8; ++r) {
#pragma unroll
      for (int q = 0; q < 4; ++q) {
        const float4 xv = *reinterpret_cast<const float4*>(&xsl[r * 260 + k + 4 * q]);
        acc[r] = fmaf(xv.x, wcur[4 * q + 0], acc[r]);
        acc[r] = fmaf(xv.y, wcur[4 * q + 1], acc[r]);
        acc[r] = fmaf(xv.z, wcur[4 * q + 2], acc[r]);
        acc[r] = fmaf(xv.w, wcur[4 * q + 3], acc[r]);
      }
    }
#pragma unroll
    for (int kk = 0; kk < 16; ++kk) wcur[kk] = wnxt[kk];
  }

  if (half == 0) {
#pragma unroll
    for (int r = 0; r < 8; ++r) red[r][j] = acc[r];
  }
  __syncthreads();
  if (half == 1) {
    const float bj = b1[j];
    const float w2j = W2[j];
#pragma unroll
    for (int r = 0; r < 8; ++r) {
      const float a = red[r][j] + acc[r] + bj;
      const float h = fmaxf(a, 0.f);
      Hbuf[(r0 + r) * 256 + j] = h;
      red[r][j] = h * w2j;               // same-thread read->write, safe
    }
  }
  __syncthreads();
  for (int s = 128; s >= 1; s >>= 1) {
    if (j < s) {
#pragma unroll
      for (int rr = 0; rr < 4; ++rr)
        red[half * 4 + rr][j] += red[half * 4 + rr][j + s];
    }
    __syncthreads();
  }
  if (half == 0 && j < 8) u[r0 + j] = red[j][0] + b2[0];
}

// ================= K2: all-wave scan + W1/b1/W2 partials =================
// 256 blocks x 256 threads; dc = blk>>5 (32 d-rows), kc = blk&31 (64 t).
// Thread = (th = tid>>7 splits t 64->32, j0 = tid&127 owns j in {j0, j0+128}).
// g is derived from h: g = (h>0) ? W2[j] : 0.  H loads double-buffered x16.
__global__ __launch_bounds__(256, 4) void scan_w1_kernel(
    const float* __restrict__ u, const float* __restrict__ ys,
    const float* __restrict__ xs, const float* __restrict__ Hbuf,
    const float* __restrict__ W2,
    float* __restrict__ pW1, float* __restrict__ pB1, float* __restrict__ pW2,
    float* __restrict__ outp) {
  const int tid = threadIdx.x;
  const int blk = blockIdx.x;
  const int dc = blk >> 5;              // 0..7
  const int kc = blk & 31;              // 0..31
  const int d0 = dc * 32;
  const int tb = kc * 64;
  const int lane = tid & 63;
  const int w = tid >> 6;               // wave id 0..3
  const int th = tid >> 7;              // t-half 0/1 (wave-uniform)
  const int j0 = tid & 127;
  const int tsl = th * 32;              // local t offset

  __shared__ __align__(16) float LDS[8704];     // 34 KB
  float* xt = LDS;                      // [0,2048): xs tile [64t][32d]
  float* c_l = LDS + 2048;              // [2048,4096): c for all 2048 t
  __shared__ float aggA[4], aggB[4], ag2A[4], ag2B[4], wsum[4];

  // ---- stage xs tile (coalesced float4, 2 per thread) ----
#pragma unroll
  for (int q = 0; q < 2; ++q) {
    const int idx = tid * 2 + q;        // 0..511
    const int row = idx >> 3;           // 0..63
    const int qd = idx & 7;
    *reinterpret_cast<float4*>(&xt[row * 32 + qd * 4]) =
        *reinterpret_cast<const float4*>(&xs[(tb + row) * 256 + d0 + qd * 4]);
  }

  // ---- prefetch H batch 0 (hides LLC latency under the scan) ----
  float hcur[16], hnxt[16];
#pragma unroll
  for (int i = 0; i < 8; ++i) {
    hcur[2 * i + 0] = Hbuf[(tb + tsl + i) * 256 + j0];
    hcur[2 * i + 1] = Hbuf[(tb + tsl + i) * 256 + j0 + 128];
  }

  // ---- scan: thread owns t in [8*tid, 8*tid+8) ----
  float e[8], kp[8];
  {
    const float4 ua = ((const float4*)u)[2 * tid];
    const float4 ub = ((const float4*)u)[2 * tid + 1];
    const float uu[8] = {ua.x, ua.y, ua.z, ua.w, ub.x, ub.y, ub.z, ub.w};
#pragma unroll
    for (int q = 0; q < 4; ++q) {
      const float4 y = ((const float4*)ys)[4 * tid + q];  // g,done,g,done
      float da = y.x - uu[2 * q];
      float db = y.z - uu[2 * q + 1];
      e[2 * q] = da * da;
      e[2 * q + 1] = db * db;
      kp[2 * q] = (y.y > 0.5f) ? 0.f : 1.f;
      kp[2 * q + 1] = (y.w > 0.5f) ? 0.f : 1.f;
    }
  }
  float A = 1.f, B = 0.f;
#pragma unroll
  for (int i = 0; i < 8; ++i) {
    const float a = kp[i] * OMA;
    B = fmaf(a, B, kp[i] * (AL * e[i]));
    A *= a;
  }
#pragma unroll
  for (int s = 1; s < 64; s <<= 1) {    // wave inclusive scan
    const float pA = __shfl_up(A, s, 64);
    const float pB = __shfl_up(B, s, 64);
    if (lane >= s) { B = fmaf(A, pB, B); A *= pA; }
  }
  if (lane == 63) { aggA[w] = A; aggB[w] = B; }
  __syncthreads();
  float rin;
  {
    float rw = 0.f;
    for (int v = 0; v < w; ++v) rw = fmaf(aggA[v], rw, aggB[v]);
    float lA = __shfl_up(A, 1, 64);
    float lB = __shfl_up(B, 1, 64);
    if (lane == 0) { lA = 1.f; lB = 0.f; }
    rin = fmaf(lA, rw, lB);
  }
  float sig[8];
  {
    float r = rin;
#pragma unroll
    for (int i = 0; i < 8; ++i) {
      sig[i] = e[i] - r;
      const float a = kp[i] * OMA;
      r = fmaf(a, r, kp[i] * (AL * e[i]));
    }
  }
  if (blk == 0 && tid == 255) outp[66049] = sig[7];   // sigmas[-1]

  float A2 = 1.f, B2 = 0.f;
#pragma unroll
  for (int i = 7; i >= 0; --i) {
    const float a = GL * kp[i];
    B2 = fmaf(a, B2, -sig[i]);
    A2 *= a;
  }
#pragma unroll
  for (int s = 1; s < 64; s <<= 1) {    // wave suffix-inclusive scan
    const float nA = __shfl_down(A2, s, 64);
    const float nB = __shfl_down(B2, s, 64);
    if (lane + s < 64) { B2 = fmaf(A2, nB, B2); A2 *= nA; }
  }
  if (lane == 0) { ag2A[w] = A2; ag2B[w] = B2; }
  __syncthreads();
  float cin;
  {
    float cw = 0.f;
    for (int v = 3; v > w; --v) cw = fmaf(ag2A[v], cw, ag2B[v]);
    float lA = __shfl_down(A2, 1, 64);
    float lB = __shfl_down(B2, 1, 64);
    if (lane == 63) { lA = 1.f; lB = 0.f; }
    cin = fmaf(lA, cw, lB);
  }
  float cr[8];
  float cc = cin, csum = 0.f;
#pragma unroll
  for (int i = 7; i >= 0; --i) {
    cc = fmaf(GL * kp[i], cc, -sig[i]);
    cr[i] = cc;
    csum += cc;
  }
  *reinterpret_cast<float4*>(&c_l[8 * tid]) = make_float4(cr[0], cr[1], cr[2], cr[3]);
  *reinterpret_cast<float4*>(&c_l[8 * tid + 4]) = make_float4(cr[4], cr[5], cr[6], cr[7]);
  if (blk == 0) {
#pragma unroll
    for (int s = 32; s >= 1; s >>= 1) csum += __shfl_xor(csum, s, 64);
    if (lane == 0) wsum[w] = csum;
  }
  __syncthreads();                      // c_l + xt ready
  if (blk == 0 && tid == 0)
    outp[66048] = wsum[0] + wsum[1] + wsum[2] + wsum[3];   // total_b2

  // ---- GEMM phase: acc[jj][d], jj in {0,1} -> j0, j0+128 ----
  const float w2a = W2[j0];
  const float w2b = W2[j0 + 128];
  float acc0[32], acc1[32];
#pragma unroll
  for (int d = 0; d < 32; ++d) { acc0[d] = 0.f; acc1[d] = 0.f; }
  float sb0 = 0.f, sb1 = 0.f, sw0 = 0.f, sw1 = 0.f;
  const bool do_bw = (dc == 0);

#pragma unroll
  for (int b = 0; b < 4; ++b) {
    if (b < 3) {
#pragma unroll
      for (int i = 0; i < 8; ++i) {
        hnxt[2 * i + 0] = Hbuf[(tb + tsl + (b + 1) * 8 + i) * 256 + j0];
        hnxt[2 * i + 1] = Hbuf[(tb + tsl + (b + 1) * 8 + i) * 256 + j0 + 128];
      }
    }
#pragma unroll
    for (int i = 0; i < 8; ++i) {
      const int tl = tsl + b * 8 + i;                 // 0..63 (wave-uniform)
      const float ct = c_l[tb + tl];                  // LDS broadcast
      const float h0 = hcur[2 * i + 0];
      const float h1 = hcur[2 * i + 1];
      const float gc0 = (h0 > 0.f) ? w2a * ct : 0.f;
      const float gc1 = (h1 > 0.f) ? w2b * ct : 0.f;
      if (do_bw) {
        sb0 += gc0; sb1 += gc1;
        sw0 = fmaf(ct, h0, sw0); sw1 = fmaf(ct, h1, sw1);
      }
#pragma unroll
      for (int q = 0; q < 8; ++q) {
        const float4 xv = *reinterpret_cast<const float4*>(&xt[tl * 32 + 4 * q]);  // broadcast
        acc0[4 * q + 0] = fmaf(gc0, xv.x, acc0[4 * q + 0]);
        acc0[4 * q + 1] = fmaf(gc0, xv.y, acc0[4 * q + 1]);
        acc0[4 * q + 2] = fmaf(gc0, xv.z, acc0[4 * q + 2]);
        acc0[4 * q + 3] = fmaf(gc0, xv.w, acc0[4 * q + 3]);
        acc1[4 * q + 0] = fmaf(gc1, xv.x, acc1[4 * q + 0]);
        acc1[4 * q + 1] = fmaf(gc1, xv.y, acc1[4 * q + 1]);
        acc1[4 * q + 2] = fmaf(gc1, xv.z, acc1[4 * q + 2]);
        acc1[4 * q + 3] = fmaf(gc1, xv.w, acc1[4 * q + 3]);
      }
    }
#pragma unroll
    for (int kk = 0; kk < 16; ++kk) hcur[kk] = hnxt[kk];
  }

  // ---- combine t-halves via LDS; th==1 stores ----
  __syncthreads();                      // xt/c_l dead; reuse LDS as comb
  if (th == 0) {
#pragma unroll
    for (int d = 0; d < 32; ++d) {
      LDS[(0 * 32 + d) * 128 + j0] = acc0[d];
      LDS[(32 + d) * 128 + j0] = acc1[d];
    }
    if (do_bw) {
      LDS[8192 + j0] = sb0;
      LDS[8192 + 128 + j0] = sb1;
      LDS[8448 + j0] = sw0;
      LDS[8448 + 128 + j0] = sw1;
    }
  }
  __syncthreads();
  if (th == 1) {
#pragma unroll
    for (int d = 0; d < 32; ++d) {
      pW1[kc * 65536 + (d0 + d) * 256 + j0] = LDS[d * 128 + j0] + acc0[d];
      pW1[kc * 65536 + (d0 + d) * 256 + j0 + 128] = LDS[(32 + d) * 128 + j0] + acc1[d];
    }
    if (do_bw) {
      pB1[kc * 256 + j0] = LDS[8192 + j0] + sb0;
      pB1[kc * 256 + j0 + 128] = LDS[8192 + 128 + j0] + sb1;
      pW2[kc * 256 + j0] = LDS[8448 + j0] + sw0;
      pW2[kc * 256 + j0 + 128] = LDS[8448 + 128 + j0] + sw1;
    }
  }
}

// ================= K3: deterministic reductions =================
// blocks 0..255: W1 columns (256 each, 32 partials, fully unrolled). block 256: b1/W2.
__global__ __launch_bounds__(256) void reduce_kernel(
    const float* __restrict__ pW1, const float* __restrict__ pB1,
    const float* __restrict__ pW2, float* __restrict__ outp) {
  if (blockIdx.x < 256) {
    const int col = blockIdx.x * 256 + threadIdx.x;
    float v[32];
#pragma unroll
    for (int k = 0; k < 32; ++k) v[k] = pW1[k * 65536 + col];  // 32 in flight
    float s = 0.f;
#pragma unroll
    for (int k = 0; k < 32; ++k) s += v[k];
    outp[col] = s;                       // total_W1
  } else {
    const int j = threadIdx.x;
    float b[32], c[32];
#pragma unroll
    for (int k = 0; k < 32; ++k) { b[k] = pB1[k * 256 + j]; c[k] = pW2[k * 256 + j]; }
    float sb = 0.f, sw = 0.f;
#pragma unroll
    for (int k = 0; k < 32; ++k) { sb += b[k]; sw += c[k]; }
    outp[65536 + j] = sb;                // total_b1
    outp[65792 + j] = sw;                // total_W2
  }
}

extern "C" void kernel_launch(void* const* d_in, const int* in_sizes, int n_in,
                              void* d_out, int out_size, void* d_ws, size_t ws_size,
                              hipStream_t stream) {
  const float* xs = (const float*)d_in[0];   // (2048, 256)
  const float* ys = (const float*)d_in[1];   // (2048, 2)
  const float* W1 = (const float*)d_in[2];   // (256, 256)
  const float* b1 = (const float*)d_in[3];   // (256,)
  const float* W2 = (const float*)d_in[4];   // (256, 1)
  const float* b2 = (const float*)d_in[5];   // (1,)
  float* outp = (float*)d_out;               // 66050 floats
  float* ws = (float*)d_ws;

  if (ws_size < (size_t)WS_FLOATS * sizeof(float)) return;  // loud fail

  float* Hbuf = ws + OFF_H;
  float* ubuf = ws + OFF_U;
  float* pW1  = ws + OFF_PW1;
  float* pB1  = ws + OFF_PB1;
  float* pW2  = ws + OFF_PW2;

  fwd_kernel<<<256, 512, 0, stream>>>(xs, W1, b1, W2, b2, Hbuf, ubuf);
  scan_w1_kernel<<<256, 256, 0, stream>>>(ubuf, ys, xs, Hbuf, W2,
                                          pW1, pB1, pW2, outp);
  reduce_kernel<<<257, 256, 0, stream>>>(pW1, pB1, pW2, outp);
}